// Round 5
// baseline (385.940 us; speedup 1.0000x reference)
//
#include <hip/hip_runtime.h>
#include <stdint.h>

// PROFILING PROBE ROUND: exact R4 structure, repeated 2x inside the kernel
// (idempotent recompute) so the dispatch exceeds the harness's ~320us fill
// kernels and lands in the rocprof top-5 with real counters.
//
// LSTMConv via MFMA, fragment-major LDS, single barrier per step.
// gates(512x64) = W(512x192) @ [x;h](192x64), mfma_f32_16x16x32_bf16.
// Gate W + FC W persistent in VGPRs. x and h stored in LDS PRE-PACKED as
// MFMA B-fragments -> conflict-free ds_read_b128. Double-buffered ->
// ONE barrier/step.

#define T_STEPS 32
#define C_IN    64
#define HID     128
#define OUT_F   64
#define BP      64
#define NBLK    256            // 16384 / BP
#define NTHR    512            // 8 waves
#define NREP    2              // profiling repeat

typedef __attribute__((ext_vector_type(8))) short short8_t;
typedef __attribute__((ext_vector_type(4))) short short4_t;
typedef __attribute__((ext_vector_type(4))) float float4_t;
typedef __attribute__((ext_vector_type(4))) unsigned int uint4_t;

__device__ __forceinline__ short f2bf(float f) {
    uint32_t u = __builtin_bit_cast(uint32_t, f);
    u += 0x7fff + ((u >> 16) & 1);   // RNE
    return (short)(u >> 16);
}
__device__ __forceinline__ uint32_t cvt_pk(float lo, float hi) {
    uint32_t r;
    asm("v_cvt_pk_bf16_f32 %0, %1, %2" : "=v"(r) : "v"(lo), "v"(hi));
    return r;
}
__device__ __forceinline__ float sigm(float x) {
    return __builtin_amdgcn_rcpf(1.0f + __expf(-x));
}
__device__ __forceinline__ float tanh_(float x) {
    float ax = fabsf(x);
    float e  = __expf(-2.0f * ax);
    float t  = (1.0f - e) * __builtin_amdgcn_rcpf(1.0f + e);
    return copysignf(t, x);
}

__global__ __launch_bounds__(NTHR, 2) void lstmconv_mfma(
    const float* __restrict__ feats,
    const float* __restrict__ W_ih,
    const float* __restrict__ W_hh,
    const float* __restrict__ b_ih,
    const float* __restrict__ b_hh,
    const float* __restrict__ fc_w,
    const float* __restrict__ fc_b,
    float* __restrict__ out)
{
    __shared__ __align__(16) short xB[2][8][512];    // 16 KB
    __shared__ __align__(16) short hB[2][16][512];   // 32 KB
    __shared__ __align__(16) float bias_s[4 * HID];  // 2 KB

    const int tid  = threadIdx.x;
    const int lane = tid & 63;
    const int wv   = tid >> 6;
    const int i16  = lane & 15;
    const int g4   = lane >> 4;
    const int p0   = blockIdx.x * BP;

    bias_s[tid] = b_ih[tid] + b_hh[tid];             // 512 == NTHR

    // Gate-W A-fragments, persistent: row = 128*gi + 16*wv + i16;
    // k = 32*kt + 8*g4 + e  (kt<2 -> W_ih)
    short8_t wfrag[4][6];
    #pragma unroll
    for (int gi = 0; gi < 4; ++gi) {
        int row = 128 * gi + 16 * wv + i16;
        #pragma unroll
        for (int kt = 0; kt < 6; ++kt) {
            int kk = 32 * kt + 8 * g4;
            const float* src = (kt < 2) ? &W_ih[row * C_IN + kk]
                                        : &W_hh[row * HID + (kk - 64)];
            short8_t f;
            #pragma unroll
            for (int e = 0; e < 8; ++e) f[e] = f2bf(src[e]);
            wfrag[gi][kt] = f;
        }
    }

    const int m2  = wv & 3;
    const int ntb = (wv >> 2) << 1;
    short8_t fcfrag[4];
    #pragma unroll
    for (int kt = 0; kt < 4; ++kt) {
        int kk = 32 * kt + 8 * g4;
        const float* src = &fc_w[(16 * m2 + i16) * HID + kk];
        short8_t f;
        #pragma unroll
        for (int e = 0; e < 8; ++e) f[e] = f2bf(src[e]);
        fcfrag[kt] = f;
    }
    const float4_t fcb = *(const float4_t*)&fc_b[16 * m2 + 4 * g4];

    const int prow  = 2 * (p0 >> 7) + 1;
    const int pcol0 = 2 * (p0 & 127) + 1;
    const int gbase = prow * 256 + pcol0 + 2 * lane;
    const int xtile = (wv >> 2) * 4 + (lane >> 4);
    const int xoff  = ((lane & 15) + 16 * (wv & 3)) * 8;
    const int htile_base = (wv >> 1) * 4;
    const int hoff  = (i16 + 16 * (2 * (wv & 1) + (g4 >> 1))) * 8 + 4 * (g4 & 1);

    auto do_fc = [&](int tf, int cb) {
        float4_t facc[2];
        facc[0] = fcb; facc[1] = fcb;
        #pragma unroll
        for (int kt = 0; kt < 4; ++kt) {
            #pragma unroll
            for (int nj = 0; nj < 2; ++nj) {
                short8_t b = *(const short8_t*)&hB[cb][kt * 4 + ntb + nj][lane * 8];
                facc[nj] = __builtin_amdgcn_mfma_f32_16x16x32_bf16(
                    fcfrag[kt], b, facc[nj], 0, 0, 0);
            }
        }
        #pragma unroll
        for (int nj = 0; nj < 2; ++nj)
            #pragma unroll
            for (int r = 0; r < 4; ++r)
                out[((size_t)(tf * OUT_F + 16 * m2 + 4 * g4 + r) << 14)
                    + p0 + 16 * (ntb + nj) + i16] = facc[nj][r];
    };

    #pragma unroll 1
    for (int rep = 0; rep < NREP; ++rep) {
        // re-zero h_{-1} region (pass 2 must restart the recurrence)
        for (int i = tid; i < 2 * 16 * 512 / 2; i += NTHR)
            ((uint32_t*)hB)[i] = 0u;
        __syncthreads();

        // prologue: gather x_0 -> xB[0]
        {
            float g[8];
            #pragma unroll
            for (int e = 0; e < 8; ++e)
                g[e] = feats[((size_t)(8 * wv + e) << 16) + gbase];
            uint4_t pk = { cvt_pk(g[0], g[1]), cvt_pk(g[2], g[3]),
                           cvt_pk(g[4], g[5]), cvt_pk(g[6], g[7]) };
            *(uint4_t*)&xB[0][xtile][xoff] = pk;
        }

        float4_t c[4];
        #pragma unroll
        for (int nt = 0; nt < 4; ++nt) c[nt] = (float4_t){0.f, 0.f, 0.f, 0.f};

        __syncthreads();   // xB[0] ready, hB zeroed

        #pragma unroll 1
        for (int t = 0; t < T_STEPS; ++t) {
            const int cur = t & 1;
            const int nxt = cur ^ 1;

            float g[8];
            if (t < T_STEPS - 1) {
                #pragma unroll
                for (int e = 0; e < 8; ++e)
                    g[e] = feats[((size_t)((t + 1) * C_IN + 8 * wv + e) << 16) + gbase];
            }

            if (t > 0) do_fc(t - 1, cur);

            float4_t acc[4][4];
            #pragma unroll
            for (int gi = 0; gi < 4; ++gi) {
                float4_t bv = *(const float4_t*)&bias_s[128 * gi + 16 * wv + 4 * g4];
                #pragma unroll
                for (int nt = 0; nt < 4; ++nt) acc[gi][nt] = bv;
            }
            #pragma unroll
            for (int kt = 0; kt < 6; ++kt) {
                short8_t bfrag[4];
                #pragma unroll
                for (int nt = 0; nt < 4; ++nt) {
                    const short* src = (kt < 2) ? &xB[cur][kt * 4 + nt][0]
                                                : &hB[cur][(kt - 2) * 4 + nt][0];
                    bfrag[nt] = *(const short8_t*)&src[lane * 8];
                }
                #pragma unroll
                for (int gi = 0; gi < 4; ++gi)
                    #pragma unroll
                    for (int nt = 0; nt < 4; ++nt)
                        acc[gi][nt] = __builtin_amdgcn_mfma_f32_16x16x32_bf16(
                            wfrag[gi][kt], bfrag[nt], acc[gi][nt], 0, 0, 0);
            }

            #pragma unroll
            for (int nt = 0; nt < 4; ++nt) {
                float4_t cv = c[nt];
                float hv[4];
                #pragma unroll
                for (int r = 0; r < 4; ++r) {
                    float ig = sigm(acc[0][nt][r]);
                    float fg = sigm(acc[1][nt][r]);
                    float gg = tanh_(acc[2][nt][r]);
                    float og = sigm(acc[3][nt][r]);
                    float cn = fg * cv[r] + ig * gg;
                    cv[r] = cn;
                    hv[r] = og * tanh_(cn);
                }
                c[nt] = cv;
                uint32_t h0 = cvt_pk(hv[0], hv[1]);
                uint32_t h1 = cvt_pk(hv[2], hv[3]);
                uint32_t* dst = (uint32_t*)&hB[nxt][htile_base + nt][hoff];
                dst[0] = h0; dst[1] = h1;
            }

            if (t < T_STEPS - 1) {
                uint4_t pk = { cvt_pk(g[0], g[1]), cvt_pk(g[2], g[3]),
                               cvt_pk(g[4], g[5]), cvt_pk(g[6], g[7]) };
                *(uint4_t*)&xB[nxt][xtile][xoff] = pk;
            }

            __syncthreads();
        }

        do_fc(T_STEPS - 1, 0);
        __syncthreads();   // pass isolation: stores done before hB re-zero
    }
}

extern "C" void kernel_launch(void* const* d_in, const int* in_sizes, int n_in,
                              void* d_out, int out_size, void* d_ws, size_t ws_size,
                              hipStream_t stream) {
    const float* feats = (const float*)d_in[0];
    const float* W_ih  = (const float*)d_in[1];
    const float* W_hh  = (const float*)d_in[2];
    const float* b_ih  = (const float*)d_in[3];
    const float* b_hh  = (const float*)d_in[4];
    const float* fc_w  = (const float*)d_in[5];
    const float* fc_b  = (const float*)d_in[6];
    float* out = (float*)d_out;

    lstmconv_mfma<<<NBLK, NTHR, 0, stream>>>(feats, W_ih, W_hh, b_ih, b_hh,
                                             fc_w, fc_b, out);
}

// Round 6
// 200.280 us; speedup vs baseline: 1.9270x; 1.9270x over previous
//
#include <hip/hip_runtime.h>
#include <stdint.h>

// LSTMConv via MFMA, fragment-major LDS, single barrier per step,
// MFMA/VALU software-interleave: A-phase is nt-outer and the cell update
// U(nt-1) is issued between MFMA clusters so the VALU/trans work runs
// while the matrix pipe drains (a 16x16x32 MFMA holds its SIMD ~19 cy
// but issues in 1 cy).
// Activations use exp2 with log2(e) FOLDED INTO the gate weights/bias
// (i,f,o rows x L2E; candidate rows x 2*L2E):
//   sigmoid(a) = rcp(1 + exp2(-a'))          (3 instr, 2 trans)
//   tanh(g)    = fma(-2, rcp(1+exp2(g')), 1) (4 instr, 2 trans)
// R5 probe: MfmaUtil 23% (= FLOP floor 48us/pass), VALUBusy 43%,
// occupancy 1 block/CU (VGPR-bound; 96 VGPR of resident weights).

#define T_STEPS 32
#define C_IN    64
#define HID     128
#define OUT_F   64
#define BP      64
#define NBLK    256            // 16384 / BP
#define NTHR    512            // 8 waves

typedef __attribute__((ext_vector_type(8))) short short8_t;
typedef __attribute__((ext_vector_type(4))) short short4_t;
typedef __attribute__((ext_vector_type(4))) float float4_t;
typedef __attribute__((ext_vector_type(4))) unsigned int uint4_t;

#define L2E 1.44269504088896340736f

__device__ __forceinline__ short f2bf(float f) {
    uint32_t u = __builtin_bit_cast(uint32_t, f);
    u += 0x7fff + ((u >> 16) & 1);   // RNE
    return (short)(u >> 16);
}
__device__ __forceinline__ uint32_t cvt_pk(float lo, float hi) {
    uint32_t r;
    asm("v_cvt_pk_bf16_f32 %0, %1, %2" : "=v"(r) : "v"(lo), "v"(hi));
    return r;
}
// pre-scaled sigmoid: a' = a*log2e already
__device__ __forceinline__ float sig2(float a) {
    return __builtin_amdgcn_rcpf(1.0f + exp2f(-a));
}
// pre-scaled tanh: a' = 2*a*log2e already;  tanh = 1 - 2/(1+2^a')
__device__ __forceinline__ float th2(float a) {
    return fmaf(-2.0f, __builtin_amdgcn_rcpf(1.0f + exp2f(a)), 1.0f);
}

__global__ __launch_bounds__(NTHR, 2) void lstmconv_mfma(
    const float* __restrict__ feats,
    const float* __restrict__ W_ih,
    const float* __restrict__ W_hh,
    const float* __restrict__ b_ih,
    const float* __restrict__ b_hh,
    const float* __restrict__ fc_w,
    const float* __restrict__ fc_b,
    float* __restrict__ out)
{
    __shared__ __align__(16) short xB[2][8][512];    // 16 KB
    __shared__ __align__(16) short hB[2][16][512];   // 32 KB
    __shared__ __align__(16) float bias_s[4 * HID];  // 2 KB

    const int tid  = threadIdx.x;
    const int lane = tid & 63;
    const int wv   = tid >> 6;       // wave 0..7; owns gate rows 16wv..16wv+16
    const int i16  = lane & 15;
    const int g4   = lane >> 4;
    const int p0   = blockIdx.x * BP;

    // ---------- one-time init ----------
    for (int i = tid; i < 2 * 16 * 512 / 2; i += NTHR)
        ((uint32_t*)hB)[i] = 0u;                     // h_{-1} = 0
    // bias with exp2 scale folded (gate = tid>>7; candidate gate is 2)
    {
        float bsc = ((tid >> 7) == 2) ? 2.0f * L2E : L2E;
        bias_s[tid] = (b_ih[tid] + b_hh[tid]) * bsc;
    }

    // Gate-W A-fragments, persistent, log2e-scaled:
    // row = 128*gi + 16*wv + i16 ; k = 32*kt + 8*g4 + e  (kt<2 -> W_ih)
    short8_t wfrag[4][6];
    #pragma unroll
    for (int gi = 0; gi < 4; ++gi) {
        int row = 128 * gi + 16 * wv + i16;
        float sc = (gi == 2) ? 2.0f * L2E : L2E;
        #pragma unroll
        for (int kt = 0; kt < 6; ++kt) {
            int kk = 32 * kt + 8 * g4;
            const float* src = (kt < 2) ? &W_ih[row * C_IN + kk]
                                        : &W_hh[row * HID + (kk - 64)];
            short8_t f;
            #pragma unroll
            for (int e = 0; e < 8; ++e) f[e] = f2bf(src[e] * sc);
            wfrag[gi][kt] = f;
        }
    }

    // FC: wave handles out rows 16*m2..+16 (m2=wv&3), n-tiles {ntb, ntb+1}.
    const int m2  = wv & 3;
    const int ntb = (wv >> 2) << 1;
    short8_t fcfrag[4];
    #pragma unroll
    for (int kt = 0; kt < 4; ++kt) {
        int kk = 32 * kt + 8 * g4;
        const float* src = &fc_w[(16 * m2 + i16) * HID + kk];
        short8_t f;
        #pragma unroll
        for (int e = 0; e < 8; ++e) f[e] = f2bf(src[e]);
        fcfrag[kt] = f;
    }
    const float4_t fcb = *(const float4_t*)&fc_b[16 * m2 + 4 * g4];

    // gather: thread loads channels c = 8*wv + e, pixel p = lane
    const int prow  = 2 * (p0 >> 7) + 1;
    const int pcol0 = 2 * (p0 & 127) + 1;
    const int gbase = prow * 256 + pcol0 + 2 * lane;
    const int xtile = (wv >> 2) * 4 + (lane >> 4);
    const int xoff  = ((lane & 15) + 16 * (wv & 3)) * 8;
    const int htile_base = (wv >> 1) * 4;
    const int hoff  = (i16 + 16 * (2 * (wv & 1) + (g4 >> 1))) * 8 + 4 * (g4 & 1);

    // prologue: gather x_0 -> xB[0]
    {
        float g[8];
        #pragma unroll
        for (int e = 0; e < 8; ++e)
            g[e] = feats[((size_t)(8 * wv + e) << 16) + gbase];
        uint4_t pk = { cvt_pk(g[0], g[1]), cvt_pk(g[2], g[3]),
                       cvt_pk(g[4], g[5]), cvt_pk(g[6], g[7]) };
        *(uint4_t*)&xB[0][xtile][xoff] = pk;
    }

    float4_t c[4];
    #pragma unroll
    for (int nt = 0; nt < 4; ++nt) c[nt] = (float4_t){0.f, 0.f, 0.f, 0.f};

    auto do_fc = [&](int tf, int cb) {
        float4_t facc[2];
        facc[0] = fcb; facc[1] = fcb;
        #pragma unroll
        for (int kt = 0; kt < 4; ++kt) {
            #pragma unroll
            for (int nj = 0; nj < 2; ++nj) {
                short8_t b = *(const short8_t*)&hB[cb][kt * 4 + ntb + nj][lane * 8];
                facc[nj] = __builtin_amdgcn_mfma_f32_16x16x32_bf16(
                    fcfrag[kt], b, facc[nj], 0, 0, 0);
            }
        }
        #pragma unroll
        for (int nj = 0; nj < 2; ++nj)
            #pragma unroll
            for (int r = 0; r < 4; ++r)
                out[((size_t)(tf * OUT_F + 16 * m2 + 4 * g4 + r) << 14)
                    + p0 + 16 * (ntb + nj) + i16] = facc[nj][r];
    };

    __syncthreads();   // xB[0] ready, hB zeroed

    #pragma unroll 1
    for (int t = 0; t < T_STEPS; ++t) {
        const int cur = t & 1;
        const int nxt = cur ^ 1;

        // ---- issue gather loads for x_{t+1} (consumed at step end)
        float g[8];
        if (t < T_STEPS - 1) {
            #pragma unroll
            for (int e = 0; e < 8; ++e)
                g[e] = feats[((size_t)((t + 1) * C_IN + 8 * wv + e) << 16) + gbase];
        }

        // ---- F(t-1): FC on h_{t-1} (in hB[cur]) — warms the matrix pipe
        if (t > 0) do_fc(t - 1, cur);

        // ---- A (nt-outer) interleaved with U(nt-1)
        float4_t acc[4][4];
        #pragma unroll
        for (int gi = 0; gi < 4; ++gi) {
            float4_t bv = *(const float4_t*)&bias_s[128 * gi + 16 * wv + 4 * g4];
            #pragma unroll
            for (int nt = 0; nt < 4; ++nt) acc[gi][nt] = bv;
        }

        // cell update for one n-tile; writes h into hB[nxt]
        auto cell = [&](int nt) {
            float4_t cv = c[nt];
            float hv[4];
            #pragma unroll
            for (int r = 0; r < 4; ++r) {
                float ig = sig2(acc[0][nt][r]);
                float fg = sig2(acc[1][nt][r]);
                float cand = th2(acc[2][nt][r]);   // already 2*L2E-scaled
                float og = sig2(acc[3][nt][r]);
                float cn = fmaf(fg, cv[r], ig * cand);
                cv[r] = cn;
                hv[r] = og * th2(cn * (2.0f * L2E));
            }
            c[nt] = cv;
            uint32_t h0 = cvt_pk(hv[0], hv[1]);
            uint32_t h1 = cvt_pk(hv[2], hv[3]);
            uint32_t* dst = (uint32_t*)&hB[nxt][htile_base + nt][hoff];
            dst[0] = h0; dst[1] = h1;
        };

        #pragma unroll
        for (int nt = 0; nt < 4; ++nt) {
            short8_t bfrag[6];
            #pragma unroll
            for (int kt = 0; kt < 6; ++kt) {
                const short* src = (kt < 2) ? &xB[cur][kt * 4 + nt][0]
                                            : &hB[cur][(kt - 2) * 4 + nt][0];
                bfrag[kt] = *(const short8_t*)&src[lane * 8];
            }
            #pragma unroll
            for (int kt = 0; kt < 6; ++kt)
                #pragma unroll
                for (int gi = 0; gi < 4; ++gi)
                    acc[gi][nt] = __builtin_amdgcn_mfma_f32_16x16x32_bf16(
                        wfrag[gi][kt], bfrag[kt], acc[gi][nt], 0, 0, 0);
            // U(nt-1) VALU/trans issues while nt's MFMAs drain the pipe
            if (nt >= 1) cell(nt - 1);
        }
        cell(3);

        // ---- pack & store x_{t+1} -> xB[nxt]
        if (t < T_STEPS - 1) {
            uint4_t pk = { cvt_pk(g[0], g[1]), cvt_pk(g[2], g[3]),
                           cvt_pk(g[4], g[5]), cvt_pk(g[6], g[7]) };
            *(uint4_t*)&xB[nxt][xtile][xoff] = pk;
        }

        __syncthreads();   // {x_{t+1}, h_t} complete
    }

    // epilogue: FC on h_31 (in hB[0] after t=31)
    do_fc(T_STEPS - 1, 0);
}

extern "C" void kernel_launch(void* const* d_in, const int* in_sizes, int n_in,
                              void* d_out, int out_size, void* d_ws, size_t ws_size,
                              hipStream_t stream) {
    const float* feats = (const float*)d_in[0];
    const float* W_ih  = (const float*)d_in[1];
    const float* W_hh  = (const float*)d_in[2];
    const float* b_ih  = (const float*)d_in[3];
    const float* b_hh  = (const float*)d_in[4];
    const float* fc_w  = (const float*)d_in[5];
    const float* fc_b  = (const float*)d_in[6];
    float* out = (float*)d_out;

    lstmconv_mfma<<<NBLK, NTHR, 0, stream>>>(feats, W_ih, W_hh, b_ih, b_hh,
                                             fc_w, fc_b, out);
}

// Round 7
// 182.670 us; speedup vs baseline: 2.1128x; 1.0964x over previous
//
#include <hip/hip_runtime.h>
#include <stdint.h>

// LSTMConv via MFMA — TWO PHASE-SHIFTED CHAINS so MFMA and VALU/trans are
// both in flight in every phase (m114: pipes overlap max-not-sum).
// Chain A = p 0..31 (n-tiles 0,1), chain B = p 32..63 (n-tiles 2,3); all
// 8 waves work on both. Per step (2 barriers):
//   P1: gather-issue(t+1), FC_A(t-1), GEMM_A(t), cell_B(t-1)
//   P2: FC_B(t-1),        GEMM_B(t), cell_A(t), x-pack(t+1)
// cell work in each phase has NO dependency on that phase's MFMAs
// (acc produced a phase earlier) -> free interleave, matrix pipe drains
// under the trans-heavy cell update.
// Weights (gate W, FC W) + bias persistent in VGPRs; x/h in LDS pre-packed
// as MFMA B-fragments (conflict-free ds_read_b128), double-buffered.
// Activations exp2-folded: gate rows x L2E (candidate x 2*L2E).

#define T_STEPS 32
#define C_IN    64
#define HID     128
#define OUT_F   64
#define BP      64
#define NBLK    256            // 16384 / BP
#define NTHR    512            // 8 waves

typedef __attribute__((ext_vector_type(8))) short short8_t;
typedef __attribute__((ext_vector_type(4))) short short4_t;
typedef __attribute__((ext_vector_type(4))) float float4_t;
typedef __attribute__((ext_vector_type(4))) unsigned int uint4_t;

#define L2E 1.44269504088896340736f

__device__ __forceinline__ short f2bf(float f) {
    uint32_t u = __builtin_bit_cast(uint32_t, f);
    u += 0x7fff + ((u >> 16) & 1);   // RNE
    return (short)(u >> 16);
}
__device__ __forceinline__ uint32_t cvt_pk(float lo, float hi) {
    uint32_t r;
    asm("v_cvt_pk_bf16_f32 %0, %1, %2" : "=v"(r) : "v"(lo), "v"(hi));
    return r;
}
__device__ __forceinline__ float sig2(float a) {   // a pre-scaled by L2E
    return __builtin_amdgcn_rcpf(1.0f + exp2f(-a));
}
__device__ __forceinline__ float th2(float a) {    // a pre-scaled by 2*L2E
    return fmaf(-2.0f, __builtin_amdgcn_rcpf(1.0f + exp2f(a)), 1.0f);
}

__global__ __launch_bounds__(NTHR, 2) void lstmconv_mfma(
    const float* __restrict__ feats,
    const float* __restrict__ W_ih,
    const float* __restrict__ W_hh,
    const float* __restrict__ b_ih,
    const float* __restrict__ b_hh,
    const float* __restrict__ fc_w,
    const float* __restrict__ fc_b,
    float* __restrict__ out)
{
    __shared__ __align__(16) short xB[2][8][512];    // 16 KB
    __shared__ __align__(16) short hB[2][16][512];   // 32 KB

    const int tid  = threadIdx.x;
    const int lane = tid & 63;
    const int wv   = tid >> 6;       // wave 0..7; owns gate rows 16wv..16wv+16
    const int i16  = lane & 15;
    const int g4   = lane >> 4;
    const int p0   = blockIdx.x * BP;

    // ---------- one-time init ----------
    for (int i = tid; i < 2 * 16 * 512 / 2; i += NTHR)
        ((uint32_t*)hB)[i] = 0u;                     // h_{-1} = 0 in BOTH bufs

    // Gate-W A-fragments, persistent, log2e-scaled:
    // row = 128*gi + 16*wv + i16 ; k = 32*kt + 8*g4 + e  (kt<2 -> W_ih)
    short8_t wfrag[4][6];
    float4_t bias_r[4];
    #pragma unroll
    for (int gi = 0; gi < 4; ++gi) {
        int row = 128 * gi + 16 * wv + i16;
        float sc = (gi == 2) ? 2.0f * L2E : L2E;
        #pragma unroll
        for (int kt = 0; kt < 6; ++kt) {
            int kk = 32 * kt + 8 * g4;
            const float* src = (kt < 2) ? &W_ih[row * C_IN + kk]
                                        : &W_hh[row * HID + (kk - 64)];
            short8_t f;
            #pragma unroll
            for (int e = 0; e < 8; ++e) f[e] = f2bf(src[e] * sc);
            wfrag[gi][kt] = f;
        }
        int g0 = 128 * gi + 16 * wv + 4 * g4;
        float4_t bi = *(const float4_t*)&b_ih[g0];
        float4_t bh = *(const float4_t*)&b_hh[g0];
        #pragma unroll
        for (int r = 0; r < 4; ++r) bias_r[gi][r] = (bi[r] + bh[r]) * sc;
    }

    // FC: wave -> m-tile m2=wv&3 (out rows 16m2..+16), local n-tile wv>>2.
    const int m2  = wv & 3;
    const int nl  = wv >> 2;         // 0 or 1 within the chain
    short8_t fcfrag[4];
    #pragma unroll
    for (int kt = 0; kt < 4; ++kt) {
        int kk = 32 * kt + 8 * g4;
        const float* src = &fc_w[(16 * m2 + i16) * HID + kk];
        short8_t f;
        #pragma unroll
        for (int e = 0; e < 8; ++e) f[e] = f2bf(src[e]);
        fcfrag[kt] = f;
    }
    const float4_t fcb = *(const float4_t*)&fc_b[16 * m2 + 4 * g4];

    // gather: thread loads channels c = 8*wv + e, pixel p = lane
    const int prow  = 2 * (p0 >> 7) + 1;
    const int pcol0 = 2 * (p0 & 127) + 1;
    const int gbase = prow * 256 + pcol0 + 2 * lane;
    const int xtile = (wv >> 2) * 4 + (lane >> 4);           // kt*4 + nt
    const int xoff  = ((lane & 15) + 16 * (wv & 3)) * 8;
    const int htile_base = (wv >> 1) * 4;                    // + global nt
    const int hoff  = (i16 + 16 * (2 * (wv & 1) + (g4 >> 1))) * 8 + 4 * (g4 & 1);

    // prologue: gather x_0 -> xB[0]
    {
        float g[8];
        #pragma unroll
        for (int e = 0; e < 8; ++e)
            g[e] = feats[((size_t)(8 * wv + e) << 16) + gbase];
        uint4_t pk = { cvt_pk(g[0], g[1]), cvt_pk(g[2], g[3]),
                       cvt_pk(g[4], g[5]), cvt_pk(g[6], g[7]) };
        *(uint4_t*)&xB[0][xtile][xoff] = pk;
    }

    float4_t accA[4][2], accB[4][2], cA[2], cB[2];
    #pragma unroll
    for (int nt = 0; nt < 2; ++nt) {
        cA[nt] = (float4_t){0.f, 0.f, 0.f, 0.f};
        cB[nt] = (float4_t){0.f, 0.f, 0.f, 0.f};
    }

    // FC + store for step tf of `chain`, h in hB[hb]
    auto do_fc = [&](int tf, int hb, int chain) {
        int ntg = chain * 2 + nl;
        float4_t facc = fcb;
        #pragma unroll
        for (int kt = 0; kt < 4; ++kt) {
            short8_t b = *(const short8_t*)&hB[hb][kt * 4 + ntg][lane * 8];
            facc = __builtin_amdgcn_mfma_f32_16x16x32_bf16(
                fcfrag[kt], b, facc, 0, 0, 0);
        }
        #pragma unroll
        for (int r = 0; r < 4; ++r)
            out[((size_t)(tf * OUT_F + 16 * m2 + 4 * g4 + r) << 14)
                + p0 + 16 * ntg + i16] = facc[r];
    };

    // gates = bias + W @ [x(xb); h(hb)] for `chain`
    auto gemm = [&](float4_t (&acc)[4][2], int xb, int hb, int chain) {
        #pragma unroll
        for (int gi = 0; gi < 4; ++gi)
            #pragma unroll
            for (int nt = 0; nt < 2; ++nt) acc[gi][nt] = bias_r[gi];
        #pragma unroll
        for (int nt = 0; nt < 2; ++nt) {
            int ntg = chain * 2 + nt;
            short8_t bf[6];
            #pragma unroll
            for (int kt = 0; kt < 6; ++kt) {
                const short* src = (kt < 2) ? &xB[xb][kt * 4 + ntg][0]
                                            : &hB[hb][(kt - 2) * 4 + ntg][0];
                bf[kt] = *(const short8_t*)&src[lane * 8];
            }
            #pragma unroll
            for (int kt = 0; kt < 6; ++kt)
                #pragma unroll
                for (int gi = 0; gi < 4; ++gi)
                    acc[gi][nt] = __builtin_amdgcn_mfma_f32_16x16x32_bf16(
                        wfrag[gi][kt], bf[kt], acc[gi][nt], 0, 0, 0);
        }
    };

    // cell update (i,f,g,o) for `chain`; writes h into hB[hb]
    auto cell = [&](float4_t (&acc)[4][2], float4_t (&c)[2], int hb, int chain) {
        #pragma unroll
        for (int nt = 0; nt < 2; ++nt) {
            float4_t cv = c[nt];
            float hv[4];
            #pragma unroll
            for (int r = 0; r < 4; ++r) {
                float ig = sig2(acc[0][nt][r]);
                float fg = sig2(acc[1][nt][r]);
                float cand = th2(acc[2][nt][r]);
                float og = sig2(acc[3][nt][r]);
                float cn = fmaf(fg, cv[r], ig * cand);
                cv[r] = cn;
                hv[r] = og * th2(cn * (2.0f * L2E));
            }
            c[nt] = cv;
            uint32_t h0 = cvt_pk(hv[0], hv[1]);
            uint32_t h1 = cvt_pk(hv[2], hv[3]);
            uint32_t* dst = (uint32_t*)&hB[hb][htile_base + chain * 2 + nt][hoff];
            dst[0] = h0; dst[1] = h1;
        }
    };

    __syncthreads();   // xB[0] ready, hB zeroed

    #pragma unroll 1
    for (int t = 0; t < T_STEPS; ++t) {
        const int cur = t & 1;
        const int nxt = cur ^ 1;   // == (t-1)&1: holds h(t-1) of both chains

        // ======== P1: FC_A(t-1) + GEMM_A(t) + cell_B(t-1) ========
        float g[8];
        if (t < T_STEPS - 1) {
            #pragma unroll
            for (int e = 0; e < 8; ++e)
                g[e] = feats[((size_t)((t + 1) * C_IN + 8 * wv + e) << 16) + gbase];
        }
        if (t > 0) do_fc(t - 1, nxt, 0);
        gemm(accA, cur, nxt, 0);
        if (t > 0) cell(accB, cB, nxt, 1);   // writes hB[nxt] tiles {2,3}

        __syncthreads();   // B1

        // ======== P2: FC_B(t-1) + GEMM_B(t) + cell_A(t) ========
        if (t > 0) do_fc(t - 1, nxt, 1);
        gemm(accB, cur, nxt, 1);
        cell(accA, cA, cur, 0);              // writes hB[cur] tiles {0,1}

        if (t < T_STEPS - 1) {
            uint4_t pk = { cvt_pk(g[0], g[1]), cvt_pk(g[2], g[3]),
                           cvt_pk(g[4], g[5]), cvt_pk(g[6], g[7]) };
            *(uint4_t*)&xB[nxt][xtile][xoff] = pk;
        }

        __syncthreads();   // B2
    }

    // epilogue: cell_B(31) -> hB[1]; then FC of both chains for t=31
    cell(accB, cB, 1, 1);
    __syncthreads();
    do_fc(T_STEPS - 1, 1, 0);
    do_fc(T_STEPS - 1, 1, 1);
}

extern "C" void kernel_launch(void* const* d_in, const int* in_sizes, int n_in,
                              void* d_out, int out_size, void* d_ws, size_t ws_size,
                              hipStream_t stream) {
    const float* feats = (const float*)d_in[0];
    const float* W_ih  = (const float*)d_in[1];
    const float* W_hh  = (const float*)d_in[2];
    const float* b_ih  = (const float*)d_in[3];
    const float* b_hh  = (const float*)d_in[4];
    const float* fc_w  = (const float*)d_in[5];
    const float* fc_b  = (const float*)d_in[6];
    float* out = (float*)d_out;

    lstmconv_mfma<<<NBLK, NTHR, 0, stream>>>(feats, W_ih, W_hh, b_ih, b_hh,
                                             fc_w, fc_b, out);
}